// Round 2
// baseline (908.730 us; speedup 1.0000x reference)
//
#include <hip/hip_runtime.h>
#include <hip/hip_bf16.h>
#include <stdint.h>

// OscillatorySSMLayer — MI355X bf16-MFMA implementation.
// B=4, S=2048, D=1024, N=64, M=B*S=8192.
// Pipeline:
//   pack_A:    x[B,S,D,2] -> A_bf16[M, 2K] = [xr | xi]      (K2 = 2048)
//   pack_W*:   complex weights -> real-GEMM bf16 matrices (row = output col)
//   GEMM1:     A @ W_D   -> Dx planes [M, 2048] fp32  (stored in d_out!)
//   GEMM2:     A @ W_BG  -> BxG [M, 256] (Bxr | Bxi | gate-logit | pad)
//   recur:     256 chains x 2048 steps -> h_all bf16 [M,128], h_final -> d_out tail
//   GEMM3:     h_all @ W_C  += Dx   (accumulate in place)
//   epilogue:  in-place per-row: out_r = or*or+or, out_i = or*oi+oi, interleave

#define Mtok 8192
#define Dd   1024
#define K2   2048
#define Nn   64

typedef __bf16 bf16x8 __attribute__((ext_vector_type(8)));
typedef float f32x4 __attribute__((ext_vector_type(4)));

__device__ __forceinline__ unsigned short f2bf(float f) {
  unsigned u = __builtin_bit_cast(unsigned, f);
  u += 0x7fffu + ((u >> 16) & 1u);   // RNE
  return (unsigned short)(u >> 16);
}

// ---------------- pack kernels ----------------

__global__ __launch_bounds__(256) void pack_A_kernel(const float* __restrict__ x,
                                                     unsigned short* __restrict__ A) {
  size_t t = (size_t)blockIdx.x * 256 + threadIdx.x;      // M*512 threads
  size_t m = t >> 9;
  int d = (int)(t & 511) << 1;                            // even d
  const float4 v = *(const float4*)&x[(m * Dd + d) * 2];  // xr(d), xi(d), xr(d+1), xi(d+1)
  ushort2 re; re.x = f2bf(v.x); re.y = f2bf(v.z);
  ushort2 im; im.x = f2bf(v.y); im.y = f2bf(v.w);
  *(ushort2*)&A[m * K2 + d] = re;
  *(ushort2*)&A[m * K2 + Dd + d] = im;
}

__global__ __launch_bounds__(256) void pack_WD_kernel(const float* __restrict__ Dwr,
                                                      const float* __restrict__ Dwi,
                                                      unsigned short* __restrict__ W) {
  int t = blockIdx.x * 256 + threadIdx.x;                 // 1024*1024 threads
  int r = t >> 10, k = t & 1023;
  float wr = Dwr[t], wi = Dwi[t];
  W[(size_t)r * K2 + k]              = f2bf(wr);
  W[(size_t)r * K2 + Dd + k]         = f2bf(-wi);
  W[(size_t)(Dd + r) * K2 + k]       = f2bf(wi);
  W[(size_t)(Dd + r) * K2 + Dd + k]  = f2bf(wr);
}

__global__ __launch_bounds__(256) void pack_WBG_kernel(const float* __restrict__ Bwr,
                                                       const float* __restrict__ Bwi,
                                                       const float* __restrict__ gw,
                                                       unsigned short* __restrict__ W) {
  int t = blockIdx.x * 256 + threadIdx.x;                 // 256*2048 threads
  int r = t >> 11, k = t & 2047;
  float v;
  if (r < 64)        v = (k < Dd) ? Bwr[r * Dd + k] : -Bwi[r * Dd + (k - Dd)];
  else if (r < 128)  { int rr = r - 64;  v = (k < Dd) ? Bwi[rr * Dd + k] : Bwr[rr * Dd + (k - Dd)]; }
  else if (r < 192)  v = gw[(r - 128) * K2 + k];
  else               v = 0.0f;
  W[t] = f2bf(v);
}

__global__ __launch_bounds__(256) void pack_WC_kernel(const float* __restrict__ Cwr,
                                                      const float* __restrict__ Cwi,
                                                      unsigned short* __restrict__ W) {
  int t = blockIdx.x * 256 + threadIdx.x;                 // 2048*128 threads
  int r = t >> 7, c = t & 127;
  float v;
  if (r < Dd) v = (c < 64) ? Cwr[r * 64 + c] : -Cwi[r * 64 + (c - 64)];
  else { int d = r - Dd; v = (c < 64) ? Cwi[d * 64 + c] : Cwr[d * 64 + (c - 64)]; }
  W[t] = f2bf(v);
}

// ---------------- MFMA GEMM ----------------
// C[m,n] (+)= sum_k A[m,k] * Bt[n,k];  A:[M,K] bf16, Bt:[N,K] bf16, C:[M,N] f32.
// Block tile 128x128, BK=64, 256 threads (4 waves, one 64x64 quadrant each,
// 4x4 fragments of 16x16x32). Reg-staged LDS (correctness-first; swizzle later).
template <bool ACC>
__global__ __launch_bounds__(256) void gemm_kernel(const unsigned short* __restrict__ A,
                                                   const unsigned short* __restrict__ Bt,
                                                   float* __restrict__ C,
                                                   int N, int K) {
  __shared__ __align__(16) unsigned short ldsA[128 * 64];
  __shared__ __align__(16) unsigned short ldsB[128 * 64];
  const int tid  = threadIdx.x;
  const int wave = tid >> 6, lane = tid & 63;
  const int m0 = blockIdx.y * 128, n0 = blockIdx.x * 128;
  const int r0 = (wave >> 1) * 64, c0 = (wave & 1) * 64;  // wave quadrant
  const int lrow = lane & 15, kgrp = lane >> 4;

  f32x4 acc[4][4] = {};

  for (int k0 = 0; k0 < K; k0 += 64) {
    uint4 va[4], vb[4];
#pragma unroll
    for (int i = 0; i < 4; ++i) {
      int chunk = i * 256 + tid;           // 1024 chunks of 16B per tile
      int row = chunk >> 3;                // 8 chunks per 64-elem row
      int cof = (chunk & 7) << 3;
      va[i] = *(const uint4*)(A  + (size_t)(m0 + row) * K + k0 + cof);
      vb[i] = *(const uint4*)(Bt + (size_t)(n0 + row) * K + k0 + cof);
    }
    __syncthreads();                       // prev compute done before overwrite
#pragma unroll
    for (int i = 0; i < 4; ++i) {
      int chunk = i * 256 + tid;
      *(uint4*)&ldsA[chunk * 8] = va[i];
      *(uint4*)&ldsB[chunk * 8] = vb[i];
    }
    __syncthreads();                       // writes visible
#pragma unroll
    for (int kk = 0; kk < 64; kk += 32) {
      bf16x8 af[4], bfr[4];
#pragma unroll
      for (int i = 0; i < 4; ++i)
        af[i] = *(const bf16x8*)&ldsA[(r0 + i * 16 + lrow) * 64 + kk + kgrp * 8];
#pragma unroll
      for (int j = 0; j < 4; ++j)
        bfr[j] = *(const bf16x8*)&ldsB[(c0 + j * 16 + lrow) * 64 + kk + kgrp * 8];
#pragma unroll
      for (int i = 0; i < 4; ++i)
#pragma unroll
        for (int j = 0; j < 4; ++j)
          acc[i][j] = __builtin_amdgcn_mfma_f32_16x16x32_bf16(af[i], bfr[j], acc[i][j], 0, 0, 0);
    }
  }

  // epilogue: D mapping col = lane&15, row = (lane>>4)*4 + reg  [verified m89/m91]
#pragma unroll
  for (int i = 0; i < 4; ++i)
#pragma unroll
    for (int j = 0; j < 4; ++j) {
      int row = m0 + r0 + i * 16 + kgrp * 4;
      int col = n0 + c0 + j * 16 + lrow;
      float* cp = C + (size_t)row * N + col;
#pragma unroll
      for (int r = 0; r < 4; ++r) {
        float v = acc[i][j][r];
        if (ACC) v += cp[(size_t)r * N];
        cp[(size_t)r * N] = v;
      }
    }
}

// ---------------- recurrence ----------------
// 4 blocks (one per batch b) x 64 threads (one per n). 2048 sequential steps.
__global__ __launch_bounds__(64) void recur_kernel(const float* __restrict__ BxG,
                                                   const float* __restrict__ gate_b,
                                                   const float* __restrict__ theta,
                                                   const float* __restrict__ damping_param,
                                                   const float* __restrict__ h0,
                                                   unsigned short* __restrict__ h_all,
                                                   float* __restrict__ h_final) {
  const int b = blockIdx.x;
  const int n = threadIdx.x;
  const float ct = cosf(theta[n]);
  const float st = sinf(theta[n]);
  const float dmp = 0.5f + 0.5f / (1.0f + expf(-damping_param[n]));
  const float gbias = gate_b[n];
  float hr = h0[(b * Nn + n) * 2 + 0];
  float hi = h0[(b * Nn + n) * 2 + 1];
#pragma unroll 4
  for (int s = 0; s < 2048; ++s) {
    const size_t base = (size_t)(b * 2048 + s) * 256;
    float bxr = BxG[base + n];
    float bxi = BxG[base + 64 + n];
    float gl  = BxG[base + 128 + n] + gbias;
    float g   = 1.0f / (1.0f + expf(-gl));
    float nr = ct * hr - st * hi;
    float ni = st * hr + ct * hi;
    float keep = (1.0f - g) * dmp;
    hr = g * bxr + keep * nr;
    hi = g * bxi + keep * ni;
    const size_t hb = (size_t)(b * 2048 + s) * 128;
    h_all[hb + n]      = f2bf(hr);
    h_all[hb + 64 + n] = f2bf(hi);
  }
  h_final[(b * Nn + n) * 2 + 0] = hr;
  h_final[(b * Nn + n) * 2 + 1] = hi;
}

// ---------------- epilogue (in-place on d_out) ----------------
// buf row m holds [yr(0..1023) | yi(0..1023)]; rewrite interleaved with
// out_r = or*or+or, out_i = or*oi+oi. One block per row; read-all / barrier / write-all.
__global__ __launch_bounds__(256) void epilogue_kernel(float* __restrict__ buf) {
  const int m = blockIdx.x;
  const int t = threadIdx.x;
  float* rowp = buf + (size_t)m * K2;
  const float4 orv = *(const float4*)&rowp[t * 4];
  const float4 oiv = *(const float4*)&rowp[Dd + t * 4];
  __syncthreads();
  float4 lo, hi;
  lo.x = orv.x * orv.x + orv.x;  lo.y = orv.x * oiv.x + oiv.x;
  lo.z = orv.y * orv.y + orv.y;  lo.w = orv.y * oiv.y + oiv.y;
  hi.x = orv.z * orv.z + orv.z;  hi.y = orv.z * oiv.z + oiv.z;
  hi.z = orv.w * orv.w + orv.w;  hi.w = orv.w * oiv.w + oiv.w;
  *(float4*)&rowp[t * 8]     = lo;
  *(float4*)&rowp[t * 8 + 4] = hi;
}

// ---------------- launch ----------------

extern "C" void kernel_launch(void* const* d_in, const int* in_sizes, int n_in,
                              void* d_out, int out_size, void* d_ws, size_t ws_size,
                              hipStream_t stream) {
  const float* x     = (const float*)d_in[0];
  const float* h0    = (const float*)d_in[1];
  const float* theta = (const float*)d_in[2];
  const float* damp  = (const float*)d_in[3];
  const float* Bwr   = (const float*)d_in[4];
  const float* Bwi   = (const float*)d_in[5];
  const float* Cwr   = (const float*)d_in[6];
  const float* Cwi   = (const float*)d_in[7];
  const float* Dwr   = (const float*)d_in[8];
  const float* Dwi   = (const float*)d_in[9];
  const float* gw    = (const float*)d_in[10];
  const float* gb    = (const float*)d_in[11];
  float* out = (float*)d_out;

  char* ws = (char*)d_ws;
  unsigned short* A     = (unsigned short*)(ws);              // 33,554,432 B
  unsigned short* W_D   = (unsigned short*)(ws + 33554432);   //  8,388,608 B
  unsigned short* W_BG  = (unsigned short*)(ws + 41943040);   //  1,048,576 B
  unsigned short* W_C   = (unsigned short*)(ws + 42991616);   //    524,288 B
  float*          BxG   = (float*)(ws + 43515904);            //  8,388,608 B
  unsigned short* h_all = (unsigned short*)(ws + 51904512);   //  2,097,152 B
  // total ws use: ~54 MB

  float* Dx      = out;                  // [M, 2048] planes, transformed in place
  float* h_final = out + (size_t)Mtok * K2;  // 16,777,216 offset

  pack_A_kernel  <<<16384, 256, 0, stream>>>(x, A);
  pack_WD_kernel <<<4096,  256, 0, stream>>>(Dwr, Dwi, W_D);
  pack_WBG_kernel<<<2048,  256, 0, stream>>>(Bwr, Bwi, gw, W_BG);
  pack_WC_kernel <<<1024,  256, 0, stream>>>(Cwr, Cwi, W_C);

  gemm_kernel<false><<<dim3(16, 64), 256, 0, stream>>>(A, W_D, Dx, 2048, 2048);
  gemm_kernel<false><<<dim3(2, 64),  256, 0, stream>>>(A, W_BG, BxG, 256, 2048);
  recur_kernel<<<4, 64, 0, stream>>>(BxG, gb, theta, damp, h0, h_all, h_final);
  gemm_kernel<true> <<<dim3(16, 64), 256, 0, stream>>>(h_all, W_C, Dx, 2048, 128);
  epilogue_kernel<<<Mtok, 256, 0, stream>>>(Dx);
}

// Round 8
// 504.669 us; speedup vs baseline: 1.8006x; 1.8006x over previous
//
#include <hip/hip_runtime.h>
#include <hip/hip_bf16.h>
#include <stdint.h>

// OscillatorySSMLayer — MI355X bf16-MFMA implementation (m97-structure GEMMs).
// B=4, S=2048, D=1024, N=64, M=B*S=8192.
//   pack_A:    x[B,S,D,2] -> A_bf16[M, 2048] = [xr | xi]
//   pack_W*:   complex weights -> real-GEMM bf16 matrices (row = output col)
//   GEMM1:     A @ W_D   -> Dx planes [M, 2048] fp32 (in d_out)
//   GEMM2:     A @ W_BG  -> BxG [M, 256] (Bxr | Bxi | gate-logit | pad)
//   recur:     256 chains x 2048 steps (reg-prefetched) -> h_all bf16 [M,128]
//   GEMM3:     h_all @ W_C += Dx
//   epilogue:  in-place interleave + out_r*out+out
// GEMMs: global_load_lds width=16, linear LDS both sides (rule #21),
// 128x128 tile, BK=64, 2 barriers/K-step, bijective XCD swizzle (grids %8==0).

#define Mtok 8192
#define Dd   1024
#define K2   2048
#define Nn   64

typedef __bf16 bf16x8 __attribute__((ext_vector_type(8)));
typedef float f32x4 __attribute__((ext_vector_type(4)));

__device__ __forceinline__ unsigned short f2bf(float f) {
  unsigned u = __builtin_bit_cast(unsigned, f);
  u += 0x7fffu + ((u >> 16) & 1u);   // RNE
  return (unsigned short)(u >> 16);
}

// async global->LDS, 16B per lane; lds dest must be wave-uniform base.
#define GLOAD_LDS16(g, l)                                                  \
  __builtin_amdgcn_global_load_lds(                                        \
      (const __attribute__((address_space(1))) unsigned int*)(g),          \
      (__attribute__((address_space(3))) unsigned int*)(l), 16, 0, 0)

// ---------------- pack kernels ----------------

__global__ __launch_bounds__(256) void pack_A_kernel(const float* __restrict__ x,
                                                     unsigned short* __restrict__ A) {
  size_t t = (size_t)blockIdx.x * 256 + threadIdx.x;      // M*512 threads
  size_t m = t >> 9;
  int d = (int)(t & 511) << 1;                            // even d
  const float4 v = *(const float4*)&x[(m * Dd + d) * 2];  // xr(d), xi(d), xr(d+1), xi(d+1)
  ushort2 re; re.x = f2bf(v.x); re.y = f2bf(v.z);
  ushort2 im; im.x = f2bf(v.y); im.y = f2bf(v.w);
  *(ushort2*)&A[m * K2 + d] = re;
  *(ushort2*)&A[m * K2 + Dd + d] = im;
}

__global__ __launch_bounds__(256) void pack_WD_kernel(const float* __restrict__ Dwr,
                                                      const float* __restrict__ Dwi,
                                                      unsigned short* __restrict__ W) {
  int t = blockIdx.x * 256 + threadIdx.x;                 // 1024*1024 threads
  int r = t >> 10, k = t & 1023;
  float wr = Dwr[t], wi = Dwi[t];
  W[(size_t)r * K2 + k]              = f2bf(wr);
  W[(size_t)r * K2 + Dd + k]         = f2bf(-wi);
  W[(size_t)(Dd + r) * K2 + k]       = f2bf(wi);
  W[(size_t)(Dd + r) * K2 + Dd + k]  = f2bf(wr);
}

__global__ __launch_bounds__(256) void pack_WBG_kernel(const float* __restrict__ Bwr,
                                                       const float* __restrict__ Bwi,
                                                       const float* __restrict__ gw,
                                                       unsigned short* __restrict__ W) {
  int t = blockIdx.x * 256 + threadIdx.x;                 // 256*2048 threads
  int r = t >> 11, k = t & 2047;
  float v;
  if (r < 64)        v = (k < Dd) ? Bwr[r * Dd + k] : -Bwi[r * Dd + (k - Dd)];
  else if (r < 128)  { int rr = r - 64;  v = (k < Dd) ? Bwi[rr * Dd + k] : Bwr[rr * Dd + (k - Dd)]; }
  else if (r < 192)  v = gw[(r - 128) * K2 + k];
  else               v = 0.0f;
  W[t] = f2bf(v);
}

__global__ __launch_bounds__(256) void pack_WC_kernel(const float* __restrict__ Cwr,
                                                      const float* __restrict__ Cwi,
                                                      unsigned short* __restrict__ W) {
  int t = blockIdx.x * 256 + threadIdx.x;                 // 2048*128 threads
  int r = t >> 7, c = t & 127;
  float v;
  if (r < Dd) v = (c < 64) ? Cwr[r * 64 + c] : -Cwi[r * 64 + (c - 64)];
  else { int d = r - Dd; v = (c < 64) ? Cwi[d * 64 + c] : Cwr[d * 64 + (c - 64)]; }
  W[t] = f2bf(v);
}

// ---------------- MFMA GEMM (m97 structure) ----------------
// C[m,n] (+)= sum_k A[m,k] * Bt[n,k];  A:[M,K] bf16, Bt:[N,K] bf16, C:[M,N] f32.
// 128x128 tile, BK=64, 256 threads (4 waves, one 64x64 quadrant each, 4x4
// frags of 16x16x32). Staging: global_load_lds 16B/lane, linear LDS.
// 1-D grid, gridDim.x % 8 == 0, bijective XCD swizzle; n-index fast.
template <bool ACC>
__global__ __launch_bounds__(256) void gemm_kernel(const unsigned short* __restrict__ A,
                                                   const unsigned short* __restrict__ Bt,
                                                   float* __restrict__ C,
                                                   int N, int K, int nbx) {
  __shared__ __align__(16) unsigned short ldsA[128 * 64];
  __shared__ __align__(16) unsigned short ldsB[128 * 64];
  const int tid  = threadIdx.x;
  const int wave = tid >> 6, lane = tid & 63;

  const int nwg = gridDim.x;
  const int cpx = nwg >> 3;
  const int swz = ((blockIdx.x & 7) * cpx) + (blockIdx.x >> 3);
  const int m0 = (swz / nbx) * 128, n0 = (swz % nbx) * 128;

  const int r0 = (wave >> 1) * 64, c0 = (wave & 1) * 64;  // wave quadrant
  const int lrow = lane & 15, kgrp = lane >> 4;

  // staging: wave w owns chunks 4w..4w+3; chunk = 8 rows x 128B of a tile
  const int srow = lane >> 3;          // row within chunk
  const int scol = (lane & 7) * 8;     // element offset within row (16B units)
  const unsigned short* gA[4];
  const unsigned short* gB[4];
  unsigned short* lA[4];
  unsigned short* lB[4];
#pragma unroll
  for (int c = 0; c < 4; ++c) {
    int chunk = wave * 4 + c;
    int row = chunk * 8 + srow;
    gA[c] = A  + (size_t)(m0 + row) * K + scol;
    gB[c] = Bt + (size_t)(n0 + row) * K + scol;
    lA[c] = &ldsA[chunk * 512];        // wave-uniform
    lB[c] = &ldsB[chunk * 512];
  }

  f32x4 acc[4][4] = {};

  for (int k0 = 0; k0 < K; k0 += 64) {
    __syncthreads();                   // all waves done reading prev tile
#pragma unroll
    for (int c = 0; c < 4; ++c) {
      GLOAD_LDS16(gA[c] + k0, lA[c]);
      GLOAD_LDS16(gB[c] + k0, lB[c]);
    }
    __syncthreads();                   // drains vmcnt -> tile ready
#pragma unroll
    for (int kk = 0; kk < 64; kk += 32) {
      bf16x8 af[4], bfr[4];
#pragma unroll
      for (int i = 0; i < 4; ++i)
        af[i] = *(const bf16x8*)&ldsA[(r0 + i * 16 + lrow) * 64 + kk + kgrp * 8];
#pragma unroll
      for (int j = 0; j < 4; ++j)
        bfr[j] = *(const bf16x8*)&ldsB[(c0 + j * 16 + lrow) * 64 + kk + kgrp * 8];
#pragma unroll
      for (int i = 0; i < 4; ++i)
#pragma unroll
        for (int j = 0; j < 4; ++j)
          acc[i][j] = __builtin_amdgcn_mfma_f32_16x16x32_bf16(af[i], bfr[j], acc[i][j], 0, 0, 0);
    }
  }

  // C-write: D mapping col = lane&15, row = (lane>>4)*4 + reg  [m89/m91]
#pragma unroll
  for (int i = 0; i < 4; ++i)
#pragma unroll
    for (int j = 0; j < 4; ++j) {
      int row = m0 + r0 + i * 16 + kgrp * 4;
      int col = n0 + c0 + j * 16 + lrow;
      float* cp = C + (size_t)row * N + col;
#pragma unroll
      for (int r = 0; r < 4; ++r) {
        float v = acc[i][j][r];
        if (ACC) v += cp[(size_t)r * N];
        cp[(size_t)r * N] = v;
      }
    }
}

// ---------------- recurrence ----------------
// 4 blocks (one per batch) x 64 threads (one per n). 2048 steps, register
// double-buffered prefetch 8 steps ahead (all indices compile-time).
__global__ __launch_bounds__(64) void recur_kernel(const float* __restrict__ BxG,
                                                   const float* __restrict__ gate_b,
                                                   const float* __restrict__ theta,
                                                   const float* __restrict__ damping_param,
                                                   const float* __restrict__ h0,
                                                   unsigned short* __restrict__ h_all,
                                                   float* __restrict__ h_final) {
  const int b = blockIdx.x;
  const int n = threadIdx.x;
  const float ct = cosf(theta[n]);
  const float st = sinf(theta[n]);
  const float dmp = 0.5f + 0.5f / (1.0f + expf(-damping_param[n]));
  const float gbias = gate_b[n];
  float hr = h0[(b * Nn + n) * 2 + 0];
  float hi = h0[(b * Nn + n) * 2 + 1];
  const float* base = BxG + (size_t)b * 2048 * 256 + n;

  float ar[8], ai[8], ag[8], br_[8], bi_[8], bg_[8];

#define LOADS(R, I, G, S0)                                              \
  { _Pragma("unroll")                                                   \
    for (int j = 0; j < 8; ++j) {                                       \
      const float* p = base + (size_t)((S0) + j) * 256;                 \
      R[j] = p[0]; I[j] = p[64]; G[j] = p[128];                         \
    } }

#define COMP(R, I, G, S0)                                               \
  { _Pragma("unroll")                                                   \
    for (int j = 0; j < 8; ++j) {                                       \
      float g  = __fdividef(1.0f, 1.0f + __expf(-(G[j] + gbias)));      \
      float nr = ct * hr - st * hi;                                     \
      float ni = st * hr + ct * hi;                                     \
      float keep = (1.0f - g) * dmp;                                    \
      hr = fmaf(g, R[j], keep * nr);                                    \
      hi = fmaf(g, I[j], keep * ni);                                    \
      size_t hb = (size_t)(b * 2048 + (S0) + j) * 128;                  \
      h_all[hb + n]      = f2bf(hr);                                    \
      h_all[hb + 64 + n] = f2bf(hi);                                    \
    } }

  LOADS(ar, ai, ag, 0);
  for (int s0 = 0; s0 < 2048; s0 += 16) {
    LOADS(br_, bi_, bg_, s0 + 8);
    COMP(ar, ai, ag, s0);
    if (s0 + 16 < 2048) LOADS(ar, ai, ag, s0 + 16);
    COMP(br_, bi_, bg_, s0 + 8);
  }
#undef LOADS
#undef COMP

  h_final[(b * Nn + n) * 2 + 0] = hr;
  h_final[(b * Nn + n) * 2 + 1] = hi;
}

// ---------------- epilogue (in-place on d_out) ----------------
__global__ __launch_bounds__(256) void epilogue_kernel(float* __restrict__ buf) {
  const int m = blockIdx.x;
  const int t = threadIdx.x;
  float* rowp = buf + (size_t)m * K2;
  const float4 orv = *(const float4*)&rowp[t * 4];
  const float4 oiv = *(const float4*)&rowp[Dd + t * 4];
  __syncthreads();
  float4 lo, hi;
  lo.x = orv.x * orv.x + orv.x;  lo.y = orv.x * oiv.x + oiv.x;
  lo.z = orv.y * orv.y + orv.y;  lo.w = orv.y * oiv.y + oiv.y;
  hi.x = orv.z * orv.z + orv.z;  hi.y = orv.z * oiv.z + oiv.z;
  hi.z = orv.w * orv.w + orv.w;  hi.w = orv.w * oiv.w + oiv.w;
  *(float4*)&rowp[t * 8]     = lo;
  *(float4*)&rowp[t * 8 + 4] = hi;
}

// ---------------- launch ----------------

extern "C" void kernel_launch(void* const* d_in, const int* in_sizes, int n_in,
                              void* d_out, int out_size, void* d_ws, size_t ws_size,
                              hipStream_t stream) {
  const float* x     = (const float*)d_in[0];
  const float* h0    = (const float*)d_in[1];
  const float* theta = (const float*)d_in[2];
  const float* damp  = (const float*)d_in[3];
  const float* Bwr   = (const float*)d_in[4];
  const float* Bwi   = (const float*)d_in[5];
  const float* Cwr   = (const float*)d_in[6];
  const float* Cwi   = (const float*)d_in[7];
  const float* Dwr   = (const float*)d_in[8];
  const float* Dwi   = (const float*)d_in[9];
  const float* gw    = (const float*)d_in[10];
  const float* gb    = (const float*)d_in[11];
  float* out = (float*)d_out;

  char* ws = (char*)d_ws;
  unsigned short* A     = (unsigned short*)(ws);              // 33,554,432 B
  unsigned short* W_D   = (unsigned short*)(ws + 33554432);   //  8,388,608 B
  unsigned short* W_BG  = (unsigned short*)(ws + 41943040);   //  1,048,576 B
  unsigned short* W_C   = (unsigned short*)(ws + 42991616);   //    524,288 B
  float*          BxG   = (float*)(ws + 43515904);            //  8,388,608 B
  unsigned short* h_all = (unsigned short*)(ws + 51904512);   //  2,097,152 B

  float* Dx      = out;                      // [M, 2048] planes, in place
  float* h_final = out + (size_t)Mtok * K2;  // tail

  pack_A_kernel  <<<16384, 256, 0, stream>>>(x, A);
  pack_WD_kernel <<<4096,  256, 0, stream>>>(Dwr, Dwi, W_D);
  pack_WBG_kernel<<<2048,  256, 0, stream>>>(Bwr, Bwi, gw, W_BG);
  pack_WC_kernel <<<1024,  256, 0, stream>>>(Cwr, Cwi, W_C);

  gemm_kernel<false><<<1024, 256, 0, stream>>>(A, W_D, Dx, 2048, 2048, 16);
  gemm_kernel<false><<<128,  256, 0, stream>>>(A, W_BG, BxG, 256, 2048, 2);
  recur_kernel<<<4, 64, 0, stream>>>(BxG, gb, theta, damp, h0, h_all, h_final);
  gemm_kernel<true> <<<1024, 256, 0, stream>>>(h_all, W_C, Dx, 2048, 128, 16);
  epilogue_kernel<<<Mtok, 256, 0, stream>>>(Dx);
}

// Round 10
// 361.908 us; speedup vs baseline: 2.5109x; 1.3945x over previous
//
#include <hip/hip_runtime.h>
#include <hip/hip_bf16.h>
#include <stdint.h>

// OscillatorySSMLayer — MI355X bf16-MFMA implementation.
// B=4, S=2048, D=1024, N=64, M=B*S=8192.
//   pack_A:    x[B,S,D,2] -> A_bf16[M, 2048] = [xr | xi]
//   pack_W*:   complex weights -> real-GEMM bf16 matrices (row = output col)
//   GEMM1:     A @ W_D   -> Dx planes [M, 2048] fp32 (in d_out)
//   GEMM2:     A @ W_BG  -> BxG [M, 256] (Bxr | Bxi | gate-logit | pad)
//   recur:     PARALLEL AFFINE SCAN (p1 chunk-compose, p2 chain-scan, p3 replay)
//   GEMM3:     h_all @ W_C += Dx
//   epilogue:  in-place interleave + out_r*out+out
// GEMMs: m97 structure (global_load_lds w=16, linear LDS, 128x128, BK=64).

#define Mtok 8192
#define Dd   1024
#define K2   2048
#define Nn   64

typedef __bf16 bf16x8 __attribute__((ext_vector_type(8)));
typedef float f32x4 __attribute__((ext_vector_type(4)));

__device__ __forceinline__ unsigned short f2bf(float f) {
  unsigned u = __builtin_bit_cast(unsigned, f);
  u += 0x7fffu + ((u >> 16) & 1u);   // RNE
  return (unsigned short)(u >> 16);
}

// async global->LDS, 16B per lane; lds dest must be wave-uniform base.
#define GLOAD_LDS16(g, l)                                                  \
  __builtin_amdgcn_global_load_lds(                                        \
      (const __attribute__((address_space(1))) unsigned int*)(g),          \
      (__attribute__((address_space(3))) unsigned int*)(l), 16, 0, 0)

// ---------------- pack kernels ----------------

__global__ __launch_bounds__(256) void pack_A_kernel(const float* __restrict__ x,
                                                     unsigned short* __restrict__ A) {
  size_t t = (size_t)blockIdx.x * 256 + threadIdx.x;      // M*512 threads
  size_t m = t >> 9;
  int d = (int)(t & 511) << 1;                            // even d
  const float4 v = *(const float4*)&x[(m * Dd + d) * 2];  // xr(d), xi(d), xr(d+1), xi(d+1)
  ushort2 re; re.x = f2bf(v.x); re.y = f2bf(v.z);
  ushort2 im; im.x = f2bf(v.y); im.y = f2bf(v.w);
  *(ushort2*)&A[m * K2 + d] = re;
  *(ushort2*)&A[m * K2 + Dd + d] = im;
}

__global__ __launch_bounds__(256) void pack_WD_kernel(const float* __restrict__ Dwr,
                                                      const float* __restrict__ Dwi,
                                                      unsigned short* __restrict__ W) {
  int t = blockIdx.x * 256 + threadIdx.x;                 // 1024*1024 threads
  int r = t >> 10, k = t & 1023;
  float wr = Dwr[t], wi = Dwi[t];
  W[(size_t)r * K2 + k]              = f2bf(wr);
  W[(size_t)r * K2 + Dd + k]         = f2bf(-wi);
  W[(size_t)(Dd + r) * K2 + k]       = f2bf(wi);
  W[(size_t)(Dd + r) * K2 + Dd + k]  = f2bf(wr);
}

__global__ __launch_bounds__(256) void pack_WBG_kernel(const float* __restrict__ Bwr,
                                                       const float* __restrict__ Bwi,
                                                       const float* __restrict__ gw,
                                                       unsigned short* __restrict__ W) {
  int t = blockIdx.x * 256 + threadIdx.x;                 // 256*2048 threads
  int r = t >> 11, k = t & 2047;
  float v;
  if (r < 64)        v = (k < Dd) ? Bwr[r * Dd + k] : -Bwi[r * Dd + (k - Dd)];
  else if (r < 128)  { int rr = r - 64;  v = (k < Dd) ? Bwi[rr * Dd + k] : Bwr[rr * Dd + (k - Dd)]; }
  else if (r < 192)  v = gw[(r - 128) * K2 + k];
  else               v = 0.0f;
  W[t] = f2bf(v);
}

__global__ __launch_bounds__(256) void pack_WC_kernel(const float* __restrict__ Cwr,
                                                      const float* __restrict__ Cwi,
                                                      unsigned short* __restrict__ W) {
  int t = blockIdx.x * 256 + threadIdx.x;                 // 2048*128 threads
  int r = t >> 7, c = t & 127;
  float v;
  if (r < Dd) v = (c < 64) ? Cwr[r * 64 + c] : -Cwi[r * 64 + (c - 64)];
  else { int d = r - Dd; v = (c < 64) ? Cwi[d * 64 + c] : Cwr[d * 64 + (c - 64)]; }
  W[t] = f2bf(v);
}

// ---------------- MFMA GEMM (m97 structure) ----------------
template <bool ACC>
__global__ __launch_bounds__(256) void gemm_kernel(const unsigned short* __restrict__ A,
                                                   const unsigned short* __restrict__ Bt,
                                                   float* __restrict__ C,
                                                   int N, int K, int nbx) {
  __shared__ __align__(16) unsigned short ldsA[128 * 64];
  __shared__ __align__(16) unsigned short ldsB[128 * 64];
  const int tid  = threadIdx.x;
  const int wave = tid >> 6, lane = tid & 63;

  const int nwg = gridDim.x;
  const int cpx = nwg >> 3;
  const int swz = ((blockIdx.x & 7) * cpx) + (blockIdx.x >> 3);
  const int m0 = (swz / nbx) * 128, n0 = (swz % nbx) * 128;

  const int r0 = (wave >> 1) * 64, c0 = (wave & 1) * 64;  // wave quadrant
  const int lrow = lane & 15, kgrp = lane >> 4;

  const int srow = lane >> 3;          // row within chunk
  const int scol = (lane & 7) * 8;     // element offset within row
  const unsigned short* gA[4];
  const unsigned short* gB[4];
  unsigned short* lA[4];
  unsigned short* lB[4];
#pragma unroll
  for (int c = 0; c < 4; ++c) {
    int chunk = wave * 4 + c;
    int row = chunk * 8 + srow;
    gA[c] = A  + (size_t)(m0 + row) * K + scol;
    gB[c] = Bt + (size_t)(n0 + row) * K + scol;
    lA[c] = &ldsA[chunk * 512];        // wave-uniform
    lB[c] = &ldsB[chunk * 512];
  }

  f32x4 acc[4][4] = {};

  for (int k0 = 0; k0 < K; k0 += 64) {
    __syncthreads();                   // all waves done reading prev tile
#pragma unroll
    for (int c = 0; c < 4; ++c) {
      GLOAD_LDS16(gA[c] + k0, lA[c]);
      GLOAD_LDS16(gB[c] + k0, lB[c]);
    }
    __syncthreads();                   // drains vmcnt -> tile ready
#pragma unroll
    for (int kk = 0; kk < 64; kk += 32) {
      bf16x8 af[4], bfr[4];
#pragma unroll
      for (int i = 0; i < 4; ++i)
        af[i] = *(const bf16x8*)&ldsA[(r0 + i * 16 + lrow) * 64 + kk + kgrp * 8];
#pragma unroll
      for (int j = 0; j < 4; ++j)
        bfr[j] = *(const bf16x8*)&ldsB[(c0 + j * 16 + lrow) * 64 + kk + kgrp * 8];
#pragma unroll
      for (int i = 0; i < 4; ++i)
#pragma unroll
        for (int j = 0; j < 4; ++j)
          acc[i][j] = __builtin_amdgcn_mfma_f32_16x16x32_bf16(af[i], bfr[j], acc[i][j], 0, 0, 0);
    }
  }

  // C-write: D mapping col = lane&15, row = (lane>>4)*4 + reg  [m89/m91]
#pragma unroll
  for (int i = 0; i < 4; ++i)
#pragma unroll
    for (int j = 0; j < 4; ++j) {
      int row = m0 + r0 + i * 16 + kgrp * 4;
      int col = n0 + c0 + j * 16 + lrow;
      float* cp = C + (size_t)row * N + col;
#pragma unroll
      for (int r = 0; r < 4; ++r) {
        float v = acc[i][j][r];
        if (ACC) v += cp[(size_t)r * N];
        cp[(size_t)r * N] = v;
      }
    }
}

// ---------------- recurrence: parallel affine scan ----------------
// h_t = a_t*h_{t-1} + b_t (complex), a_t = (1-g)*dmp*e^{i*theta}, b_t = g*Bx_t.
// 128 chunks x 16 steps per chain. |a_t| < 0.77 -> stable composition.
// AB layout [b][c][4][64] (Ar,Ai,Br,Bi planes); Hst layout [b][c][2][64].

__global__ __launch_bounds__(64) void recur_p1(const float* __restrict__ BxG,
                                               const float* __restrict__ gate_b,
                                               const float* __restrict__ theta,
                                               const float* __restrict__ damping_param,
                                               float* __restrict__ AB) {
  const int n = threadIdx.x;
  const int b = blockIdx.x >> 7;
  const int c = blockIdx.x & 127;
  const float ct = cosf(theta[n]), st = sinf(theta[n]);
  const float dmp = 0.5f + 0.5f / (1.0f + expf(-damping_param[n]));
  const float gbias = gate_b[n];
  const float* base = BxG + ((size_t)(b * 2048 + c * 16) * 256) + n;

  float r[16], im[16], gl[16];
#pragma unroll
  for (int j = 0; j < 16; ++j) {
    const float* p = base + j * 256;
    r[j] = p[0]; im[j] = p[64]; gl[j] = p[128];
  }
  float Ar = 1.f, Ai = 0.f, Br = 0.f, Bi = 0.f;
#pragma unroll
  for (int j = 0; j < 16; ++j) {
    float g    = __fdividef(1.f, 1.f + __expf(-(gl[j] + gbias)));
    float keep = (1.f - g) * dmp;
    float ar = keep * ct, ai = keep * st;
    float nAr = ar * Ar - ai * Ai;
    float nAi = ar * Ai + ai * Ar;
    float nBr = ar * Br - ai * Bi + g * r[j];
    float nBi = ar * Bi + ai * Br + g * im[j];
    Ar = nAr; Ai = nAi; Br = nBr; Bi = nBi;
  }
  size_t o = ((size_t)(b * 128 + c) * 4) * 64 + n;
  AB[o] = Ar; AB[o + 64] = Ai; AB[o + 128] = Br; AB[o + 192] = Bi;
}

__global__ __launch_bounds__(64) void recur_p2(const float* __restrict__ AB,
                                               const float* __restrict__ h0,
                                               float* __restrict__ Hst,
                                               float* __restrict__ h_final) {
  const int n = threadIdx.x;
  const int b = blockIdx.x;
  float hr = h0[(b * Nn + n) * 2], hi = h0[(b * Nn + n) * 2 + 1];
#pragma unroll 4
  for (int c = 0; c < 128; ++c) {
    size_t o  = ((size_t)(b * 128 + c) * 4) * 64 + n;
    float Ar = AB[o], Ai = AB[o + 64], Br = AB[o + 128], Bi = AB[o + 192];
    size_t ho = ((size_t)(b * 128 + c) * 2) * 64 + n;
    Hst[ho] = hr; Hst[ho + 64] = hi;
    float nhr = Ar * hr - Ai * hi + Br;
    float nhi = Ar * hi + Ai * hr + Bi;
    hr = nhr; hi = nhi;
  }
  h_final[(b * Nn + n) * 2]     = hr;
  h_final[(b * Nn + n) * 2 + 1] = hi;
}

__global__ __launch_bounds__(64) void recur_p3(const float* __restrict__ BxG,
                                               const float* __restrict__ gate_b,
                                               const float* __restrict__ theta,
                                               const float* __restrict__ damping_param,
                                               const float* __restrict__ Hst,
                                               unsigned short* __restrict__ h_all) {
  const int n = threadIdx.x;
  const int b = blockIdx.x >> 7;
  const int c = blockIdx.x & 127;
  const float ct = cosf(theta[n]), st = sinf(theta[n]);
  const float dmp = 0.5f + 0.5f / (1.0f + expf(-damping_param[n]));
  const float gbias = gate_b[n];
  const float* base = BxG + ((size_t)(b * 2048 + c * 16) * 256) + n;

  float r[16], im[16], gl[16];
#pragma unroll
  for (int j = 0; j < 16; ++j) {
    const float* p = base + j * 256;
    r[j] = p[0]; im[j] = p[64]; gl[j] = p[128];
  }
  size_t ho = ((size_t)(b * 128 + c) * 2) * 64 + n;
  float hr = Hst[ho], hi = Hst[ho + 64];
#pragma unroll
  for (int j = 0; j < 16; ++j) {
    float g    = __fdividef(1.f, 1.f + __expf(-(gl[j] + gbias)));
    float keep = (1.f - g) * dmp;
    float nr = ct * hr - st * hi;
    float ni = st * hr + ct * hi;
    hr = fmaf(g, r[j],  keep * nr);
    hi = fmaf(g, im[j], keep * ni);
    size_t hb = (size_t)(b * 2048 + c * 16 + j) * 128;
    h_all[hb + n]      = f2bf(hr);
    h_all[hb + 64 + n] = f2bf(hi);
  }
}

// ---------------- epilogue (in-place on d_out) ----------------
__global__ __launch_bounds__(256) void epilogue_kernel(float* __restrict__ buf) {
  const int m = blockIdx.x;
  const int t = threadIdx.x;
  float* rowp = buf + (size_t)m * K2;
  const float4 orv = *(const float4*)&rowp[t * 4];
  const float4 oiv = *(const float4*)&rowp[Dd + t * 4];
  __syncthreads();
  float4 lo, hi;
  lo.x = orv.x * orv.x + orv.x;  lo.y = orv.x * oiv.x + oiv.x;
  lo.z = orv.y * orv.y + orv.y;  lo.w = orv.y * oiv.y + oiv.y;
  hi.x = orv.z * orv.z + orv.z;  hi.y = orv.z * oiv.z + oiv.z;
  hi.z = orv.w * orv.w + orv.w;  hi.w = orv.w * oiv.w + oiv.w;
  *(float4*)&rowp[t * 8]     = lo;
  *(float4*)&rowp[t * 8 + 4] = hi;
}

// ---------------- launch ----------------

extern "C" void kernel_launch(void* const* d_in, const int* in_sizes, int n_in,
                              void* d_out, int out_size, void* d_ws, size_t ws_size,
                              hipStream_t stream) {
  const float* x     = (const float*)d_in[0];
  const float* h0    = (const float*)d_in[1];
  const float* theta = (const float*)d_in[2];
  const float* damp  = (const float*)d_in[3];
  const float* Bwr   = (const float*)d_in[4];
  const float* Bwi   = (const float*)d_in[5];
  const float* Cwr   = (const float*)d_in[6];
  const float* Cwi   = (const float*)d_in[7];
  const float* Dwr   = (const float*)d_in[8];
  const float* Dwi   = (const float*)d_in[9];
  const float* gw    = (const float*)d_in[10];
  const float* gb    = (const float*)d_in[11];
  float* out = (float*)d_out;

  char* ws = (char*)d_ws;
  unsigned short* A     = (unsigned short*)(ws);              // 33,554,432 B
  unsigned short* W_D   = (unsigned short*)(ws + 33554432);   //  8,388,608 B
  unsigned short* W_BG  = (unsigned short*)(ws + 41943040);   //  1,048,576 B
  unsigned short* W_C   = (unsigned short*)(ws + 42991616);   //    524,288 B
  float*          BxG   = (float*)(ws + 43515904);            //  8,388,608 B
  unsigned short* h_all = (unsigned short*)(ws + 51904512);   //  2,097,152 B
  // scan scratch overlaps A's region (A is dead after GEMM2, stream-ordered):
  float*          AB    = (float*)(ws);                       //    524,288 B
  float*          Hst   = (float*)(ws + 524288);              //    262,144 B

  float* Dx      = out;                      // [M, 2048] planes, in place
  float* h_final = out + (size_t)Mtok * K2;  // tail

  pack_A_kernel  <<<16384, 256, 0, stream>>>(x, A);
  pack_WD_kernel <<<4096,  256, 0, stream>>>(Dwr, Dwi, W_D);
  pack_WBG_kernel<<<2048,  256, 0, stream>>>(Bwr, Bwi, gw, W_BG);
  pack_WC_kernel <<<1024,  256, 0, stream>>>(Cwr, Cwi, W_C);

  gemm_kernel<false><<<1024, 256, 0, stream>>>(A, W_D, Dx, 2048, 2048, 16);
  gemm_kernel<false><<<128,  256, 0, stream>>>(A, W_BG, BxG, 256, 2048, 2);

  recur_p1<<<512, 64, 0, stream>>>(BxG, gb, theta, damp, AB);
  recur_p2<<<4,   64, 0, stream>>>(AB, h0, Hst, h_final);
  recur_p3<<<512, 64, 0, stream>>>(BxG, gb, theta, damp, Hst, h_all);

  gemm_kernel<true> <<<1024, 256, 0, stream>>>(h_all, W_C, Dx, 2048, 128, 16);
  epilogue_kernel<<<Mtok, 256, 0, stream>>>(Dx);
}